// Round 12
// baseline (363.632 us; speedup 1.0000x reference)
//
#include <hip/hip_runtime.h>
#include <hip/hip_bf16.h>

#define NN    50000
#define NUSER 40000
#define EE    400000
#define KKIND 3
#define HHEAD 4
#define FIN   128
#define FOUT  64
#define NCLS  40

#define CHK  32            // edge chunks per kind
#define CHE  (EE / CHK)    // 12500 edges per chunk
#define HALF 20000         // targets per half
#define HWRD 10000         // packed u16-pair words per half

typedef __attribute__((ext_vector_type(8))) short short8;
typedef __attribute__((ext_vector_type(4))) float floatx4;

__device__ __forceinline__ float bf2f(unsigned short u) {
    unsigned int v = ((unsigned int)u) << 16;
    return __uint_as_float(v);
}
__device__ __forceinline__ unsigned short f2bf(float f) {
    unsigned int u = __float_as_uint(f);
    unsigned int r = (u + 0x7FFFu + ((u >> 16) & 1u)) >> 16;  // RNE
    return (unsigned short)r;
}

// conv-region element offsets (u16 elements) — all multiples of 8
#define OFF_H    0
#define OFF_W    6400000
#define OFF_ASRC 6498304
#define OFF_ATRG 6499072
#define OFF_W1   6499840
#define OFF_W2   6508032
#define OFF_M    6512128
#define OFF_FCW  6512192
#define OFF_FCB  6522432
#define CONV_TOT 6522472

// ---------------------------------------------------------------------------
// dtype detect (f32 vs bf16 float inputs)
// ---------------------------------------------------------------------------
__global__ __launch_bounds__(256) void detect_kernel(const unsigned short* __restrict__ hraw,
                                                     int* __restrict__ flag)
{
    __shared__ int cnt;
    if (threadIdx.x == 0) cnt = 0;
    __syncthreads();
    int local = 0;
#pragma unroll
    for (int j = 0; j < 8; j++) {
        unsigned short u = hraw[threadIdx.x * 8 + j];
        int ex = (u >> 7) & 0xFF;
        if (ex >= 0x90) local++;
    }
    atomicAdd(&cnt, local);
    __syncthreads();
    if (threadIdx.x == 0) *flag = (cnt > 100) ? 1 : 0;
}

// 8 u16 elements per thread; segment boundaries all %8==0
__global__ __launch_bounds__(256) void conv_kernel(const void* __restrict__ p0, const void* __restrict__ p2,
                                                   const void* __restrict__ p3, const void* __restrict__ p4,
                                                   const void* __restrict__ p5, const void* __restrict__ p6,
                                                   const void* __restrict__ p7, const void* __restrict__ p8,
                                                   const void* __restrict__ p9,
                                                   const int* __restrict__ flagp,
                                                   unsigned short* __restrict__ dst)
{
    int tid = (blockIdx.x * 256 + threadIdx.x) * 8;
    if (tid >= CONV_TOT) return;
    const void* src; int li;
    if      (tid < OFF_W)    { src = p0; li = tid - OFF_H; }
    else if (tid < OFF_ASRC) { src = p2; li = tid - OFF_W; }
    else if (tid < OFF_ATRG) { src = p3; li = tid - OFF_ASRC; }
    else if (tid < OFF_W1)   { src = p4; li = tid - OFF_ATRG; }
    else if (tid < OFF_W2)   { src = p5; li = tid - OFF_W1; }
    else if (tid < OFF_M)    { src = p6; li = tid - OFF_W2; }
    else if (tid < OFF_FCW)  { src = p7; li = tid - OFF_M; }
    else if (tid < OFF_FCB)  { src = p8; li = tid - OFF_FCW; }
    else                     { src = p9; li = tid - OFF_FCB; }
    if (*flagp) {
        const float* fp = (const float*)src + li;
        float4 x = *(const float4*)fp;
        float4 y = *(const float4*)(fp + 4);
        uint4 o;
        o.x = (unsigned int)f2bf(x.x) | ((unsigned int)f2bf(x.y) << 16);
        o.y = (unsigned int)f2bf(x.z) | ((unsigned int)f2bf(x.w) << 16);
        o.z = (unsigned int)f2bf(y.x) | ((unsigned int)f2bf(y.y) << 16);
        o.w = (unsigned int)f2bf(y.z) | ((unsigned int)f2bf(y.w) << 16);
        *(uint4*)(dst + tid) = o;
    } else {
        *(uint4*)(dst + tid) = *(const uint4*)((const unsigned short*)src + li);
    }
}

// ---------------------------------------------------------------------------
// B-matrix repacks into MFMA fragment layout
// ---------------------------------------------------------------------------
__global__ __launch_bounds__(256) void repack_w(const unsigned short* __restrict__ w,
                                                unsigned short* __restrict__ wT)
{
    int tid = blockIdx.x * 256 + threadIdx.x;       // 3*4*16*64 = 12288
    if (tid >= 12288) return;
    int f = tid & 63, g = (tid >> 6) & 15, h = (tid >> 10) & 3, k = tid >> 12;
    const unsigned short* src = w + (size_t)(k * 4 + h) * 8192 + f;
    unsigned short* dst = wT + (size_t)tid * 8;
#pragma unroll
    for (int j = 0; j < 8; j++) dst[j] = src[(size_t)(g * 8 + j) * 64];
}

__global__ __launch_bounds__(256) void repack_small(const unsigned short* __restrict__ w1,
                                                    const unsigned short* __restrict__ w2,
                                                    const unsigned short* __restrict__ fcw,
                                                    unsigned short* __restrict__ w1T,
                                                    unsigned short* __restrict__ w2T,
                                                    unsigned short* __restrict__ fcwT)
{
    int tid = blockIdx.x * 256 + threadIdx.x;
    if (tid < 1024) {
        int c = tid & 63, g = tid >> 6;
#pragma unroll
        for (int j = 0; j < 8; j++) w1T[(size_t)(g * 64 + c) * 8 + j] = w1[(size_t)(g * 8 + j) * 64 + c];
    } else if (tid < 1536) {
        int t = tid - 1024; int c = t & 63, g = t >> 6;
#pragma unroll
        for (int j = 0; j < 8; j++) w2T[(size_t)(g * 64 + c) * 8 + j] = w2[(size_t)(g * 8 + j) * 64 + c];
    } else if (tid < 3072) {
        int t = tid - 1536; int c = t % 48, g = t / 48;
#pragma unroll
        for (int j = 0; j < 8; j++)
            fcwT[(size_t)(g * 48 + c) * 8 + j] = (c < NCLS) ? fcw[(size_t)(g * 8 + j) * NCLS + c] : (unsigned short)0;
    }
}

// ---------------------------------------------------------------------------
// repack_ast: sparse 256x16 Bst per kind in fragment layout.
// ---------------------------------------------------------------------------
__global__ __launch_bounds__(256) void repack_ast(const unsigned short* __restrict__ asrc_all,
                                                  const unsigned short* __restrict__ atrg_all,
                                                  unsigned short* __restrict__ bst)
{
    int tid = blockIdx.x * 256 + threadIdx.x;       // 3*32*16 = 1536
    if (tid >= 1536) return;
    int c = tid & 15, g = (tid >> 4) & 31, k = tid >> 9;
    const unsigned short* ask = asrc_all + k * 256;   // [h][f]
    const unsigned short* atk = atrg_all + k * 256;
    unsigned short* dst = bst + (size_t)tid * 8;
#pragma unroll
    for (int j = 0; j < 8; j++) {
        int kd = g * 8 + j;
        int f = kd >> 2, hh = kd & 3;
        unsigned short v = 0;
        if (c < 4)      { if (hh == c)     v = ask[c * 64 + f]; }
        else if (c < 8) { if (hh == c - 4) v = atk[(c - 4) * 64 + f]; }
        dst[j] = v;
    }
}

// ---------------------------------------------------------------------------
// histL: LDS counting-sort rank pass.  Grid (CHK, 2*KKIND); block owns one
// (edge-chunk, target-half, kind).  Packed u16 counters in 40 KB LDS —
// LDS atomics (per-CU) replace the device-scope atomic-return wall.
// ---------------------------------------------------------------------------
__global__ __launch_bounds__(256) void histL(const int* __restrict__ ei,
                                             unsigned int* __restrict__ blkcnt,
                                             unsigned int* __restrict__ rank)
{
    __shared__ unsigned int lcnt[HWRD];   // 40 KB
    int b = blockIdx.x;
    int hf = blockIdx.y & 1, k = blockIdx.y >> 1;
    const int* trg = ei + (size_t)k * 2 * EE + EE;
    unsigned int* rk = rank + (size_t)k * EE;
    for (int i = threadIdx.x; i < HWRD; i += 256) lcnt[i] = 0u;
    __syncthreads();
    int base = b * CHE;
    int tbase = hf * HALF;
    for (int i = threadIdx.x; i < CHE; i += 256) {
        int e = base + i;
        int tn = trg[e];
        unsigned int lt = (unsigned int)(tn - tbase);
        if (lt < HALF) {
            unsigned int sh = (lt & 1u) * 16u;
            unsigned int old = atomicAdd(&lcnt[lt >> 1], 1u << sh);
            rk[e] = (old >> sh) & 0xFFFFu;
        }
    }
    __syncthreads();
    unsigned int* dst = blkcnt + ((size_t)(k * 2 + hf) * HWRD) * CHK + b;
    for (int w = threadIdx.x; w < HWRD; w += 256)
        dst[(size_t)w * CHK] = lcnt[w];
}

// ---------------------------------------------------------------------------
// scanD: per (kind,half,word) exclusive prefix over the CHK chunk counts
// (packed u16 pairs), in place; emits per-target totals into cnt.
// ---------------------------------------------------------------------------
__global__ __launch_bounds__(256) void scanD(unsigned int* __restrict__ blkcnt,
                                             unsigned int* __restrict__ cnt)
{
    int tid = blockIdx.x * 256 + threadIdx.x;      // KKIND*2*HWRD = 60000
    if (tid >= KKIND * 2 * HWRD) return;
    int w = tid % HWRD;
    int kh = tid / HWRD;
    int hf = kh & 1, k = kh >> 1;
    unsigned int* p = blkcnt + (size_t)tid * CHK;
    unsigned int run = 0;
#pragma unroll 8
    for (int b = 0; b < CHK; b++) {
        unsigned int v = p[b];
        p[b] = run;
        run += v;
    }
    int t = hf * HALF + w * 2;
    cnt[(size_t)k * NUSER + t]     = run & 0xFFFFu;
    cnt[(size_t)k * NUSER + t + 1] = run >> 16;
}

#define SCB 20
__global__ __launch_bounds__(256) void scanA(const unsigned int* __restrict__ cnt,
                                             unsigned int* __restrict__ partials)
{
    int k = blockIdx.y, b = blockIdx.x;
    const unsigned int* c = cnt + (size_t)k * NUSER;
    int base = b * 2048 + threadIdx.x * 8;
    unsigned int s = 0;
#pragma unroll
    for (int j = 0; j < 8; j++) { int idx = base + j; if (idx < NUSER) s += c[idx]; }
#pragma unroll
    for (int off = 1; off < 64; off <<= 1) s += __shfl_xor(s, off, 64);
    __shared__ unsigned int wsum[4];
    int lane = threadIdx.x & 63, wid = threadIdx.x >> 6;
    if (lane == 0) wsum[wid] = s;
    __syncthreads();
    if (threadIdx.x == 0) partials[k * SCB + b] = wsum[0] + wsum[1] + wsum[2] + wsum[3];
}

__global__ __launch_bounds__(256) void scanB(unsigned int* __restrict__ partials,
                                             unsigned int* __restrict__ rowptr)
{
    int wid = threadIdx.x >> 6, lane = threadIdx.x & 63;
    if (wid >= KKIND) return;
    unsigned int v = (lane < SCB) ? partials[wid * SCB + lane] : 0u;
    unsigned int inc = v;
#pragma unroll
    for (int off = 1; off < 32; off <<= 1) {
        unsigned int u = __shfl_up(inc, off, 64);
        if (lane >= off) inc += u;
    }
    if (lane < SCB) partials[wid * SCB + lane] = inc - v;
    if (lane == SCB - 1) rowptr[(size_t)wid * (NUSER + 1) + NUSER] = inc;
}

__global__ __launch_bounds__(256) void scanC(const unsigned int* __restrict__ cnt,
                                             const unsigned int* __restrict__ partials,
                                             unsigned int* __restrict__ rowptr)
{
    int k = blockIdx.y, b = blockIdx.x;
    const unsigned int* c = cnt + (size_t)k * NUSER;
    unsigned int* rp = rowptr + (size_t)k * (NUSER + 1);
    int lane = threadIdx.x & 63, wid = threadIdx.x >> 6;
    int base = b * 2048 + threadIdx.x * 8;
    unsigned int vals[8]; unsigned int s = 0;
#pragma unroll
    for (int j = 0; j < 8; j++) { int idx = base + j; vals[j] = (idx < NUSER) ? c[idx] : 0u; s += vals[j]; }
    unsigned int inc = s;
#pragma unroll
    for (int off = 1; off < 64; off <<= 1) {
        unsigned int u = __shfl_up(inc, off, 64);
        if (lane >= off) inc += u;
    }
    __shared__ unsigned int wsum[4];
    if (lane == 63) wsum[wid] = inc;
    __syncthreads();
    unsigned int woff = 0;
    for (int i = 0; i < wid; i++) woff += wsum[i];
    unsigned int run = partials[k * SCB + b] + woff + (inc - s);
#pragma unroll
    for (int j = 0; j < 8; j++) {
        int idx = base + j;
        if (idx < NUSER) { rp[idx] = run; run += vals[j]; }
    }
}

// atomic-free scatter: p = rowptr[tn] + blkpos[chunk][tn] + rank[e]
__global__ __launch_bounds__(256) void scatter3(const int* __restrict__ ei,
                                                const unsigned int* __restrict__ rowptr,
                                                const unsigned int* __restrict__ blkpos,
                                                const unsigned int* __restrict__ rank,
                                                int* __restrict__ srcl)
{
    int k = blockIdx.y;
    const int* srcA = ei + (size_t)k * 2 * EE;
    const int* trg = srcA + EE;
    const unsigned int* rp = rowptr + (size_t)k * (NUSER + 1);
    const unsigned int* rk = rank + (size_t)k * EE;
    int* sl = srcl + (size_t)k * EE;
    int e0 = blockIdx.x * 1024 + threadIdx.x;
#pragma unroll
    for (int j = 0; j < 4; j++) {
        int e = e0 + j * 256;
        if (e >= EE) continue;
        int tn = trg[e];
        if (tn >= NUSER) continue;
        int hf = (tn >= HALF) ? 1 : 0;
        int lt = tn - hf * HALF;
        int b = e / CHE;
        unsigned int pos = blkpos[((size_t)(k * 2 + hf) * HWRD + (lt >> 1)) * CHK + b];
        pos = (pos >> ((lt & 1) * 16)) & 0xFFFFu;
        sl[rp[tn] + pos + rk[e]] = srcA[e];
    }
}

// ---------------------------------------------------------------------------
// hp_gemm3: one wave per (16 rows x 16-col quadrant), looping kcnt kinds —
// A-fragments loaded once.  hp2 layout [n][f][4heads].
// ---------------------------------------------------------------------------
__global__ __launch_bounds__(256) void hp_gemm3(const unsigned short* __restrict__ h,
                                                const unsigned short* __restrict__ wTall,
                                                unsigned short* __restrict__ hp2,
                                                long long hp2_stride, int kbeg, int kcnt)
{
    int q = threadIdx.x >> 6;            // col quadrant 0..3
    int lane = threadIdx.x & 63;
    int m0 = blockIdx.x * 16;
    int mi = lane & 15, quad = lane >> 4;

    short8 a[4];
    const unsigned short* hrow = h + (size_t)(m0 + mi) * FIN + quad * 8;
#pragma unroll
    for (int kk = 0; kk < 4; kk++) a[kk] = *(const short8*)(hrow + kk * 32);

    int fc = q * 16 + mi;
    for (int kq = 0; kq < kcnt; kq++) {
        const unsigned short* wTk = wTall + (size_t)(kbeg + kq) * 32768;
        unsigned short* hp2k = hp2 + (size_t)kq * hp2_stride;
        floatx4 acc4[4];
#pragma unroll
        for (int hh = 0; hh < 4; hh++) {
            floatx4 acc = {0.f, 0.f, 0.f, 0.f};
#pragma unroll
            for (int kk = 0; kk < 4; kk++) {
                short8 b = *(const short8*)(wTk + (size_t)((hh * 16 + kk * 4 + quad) * 64 + fc) * 8);
                acc = __builtin_amdgcn_mfma_f32_16x16x32_bf16(a[kk], b, acc, 0, 0, 0);
            }
            acc4[hh] = acc;
        }
#pragma unroll
        for (int reg = 0; reg < 4; reg++) {
            ushort4 pk;
            pk.x = f2bf(acc4[0][reg]); pk.y = f2bf(acc4[1][reg]);
            pk.z = f2bf(acc4[2][reg]); pk.w = f2bf(acc4[3][reg]);
            int row = m0 + quad * 4 + reg;
            *(ushort4*)(hp2k + (size_t)row * 256 + fc * 4) = pk;
        }
    }
}

// ---------------------------------------------------------------------------
// st_gemm: [s|t](16 nodes, 8 cols) = hp2-rows @ Bst via 8 MFMAs per wave.
// ---------------------------------------------------------------------------
__global__ __launch_bounds__(256) void st_gemm(const unsigned short* __restrict__ hp2,
                                               long long hp2_stride,
                                               const unsigned short* __restrict__ bst,
                                               float* __restrict__ sb, float* __restrict__ tb,
                                               int kbeg)
{
    int kq = blockIdx.y, k = kbeg + kq;
    const unsigned short* hp2k = hp2 + (size_t)kq * hp2_stride;
    const unsigned short* bk = bst + (size_t)k * 4096;
    float* sbk = sb + (size_t)k * NN * 4;
    float* tbk = tb + (size_t)k * NN * 4;

    int wave = threadIdx.x >> 6;
    int lane = threadIdx.x & 63;
    int m0 = (blockIdx.x * 4 + wave) * 16;
    if (m0 >= NN) return;
    int mi = lane & 15, quad = lane >> 4;

    floatx4 acc = {0.f, 0.f, 0.f, 0.f};
#pragma unroll
    for (int kk = 0; kk < 8; kk++) {
        short8 a = *(const short8*)(hp2k + (size_t)(m0 + mi) * 256 + kk * 32 + quad * 8);
        short8 b = *(const short8*)(bk + (size_t)((kk * 4 + quad) * 16 + mi) * 8);
        acc = __builtin_amdgcn_mfma_f32_16x16x32_bf16(a, b, acc, 0, 0, 0);
    }
    if (mi < 8) {
#pragma unroll
        for (int reg = 0; reg < 4; reg++) {
            int n = m0 + quad * 4 + reg;
            if (mi < 4) sbk[n * 4 + mi] = acc[reg];
            else        tbk[n * 4 + (mi - 4)] = acc[reg];
        }
    }
}

// ---------------------------------------------------------------------------
// passB_multi: wave per (user node, kind); two-phase LDS-broadcast edge loop.
// ---------------------------------------------------------------------------
__global__ __launch_bounds__(256) void passB_multi(const unsigned int* __restrict__ rowptr_all,
                                                   const int* __restrict__ srcl_all,
                                                   const float* __restrict__ sb,
                                                   const float* __restrict__ tb,
                                                   const unsigned short* __restrict__ hp2,
                                                   long long hp2_stride,
                                                   unsigned short* __restrict__ ret, int kbeg)
{
    __shared__ int    lds_src[4][64];
    __shared__ float4 lds_ew[4][64];
    int kq = blockIdx.y, k = kbeg + kq;
    const unsigned int* rowptr = rowptr_all + (size_t)k * (NUSER + 1);
    const int* srcl = srcl_all + (size_t)k * EE;
    const float* sbk = sb + (size_t)k * NN * 4;
    const float* tbk = tb + (size_t)k * NN * 4;
    const unsigned short* hp2k = hp2 + (size_t)kq * hp2_stride;

    int wid = threadIdx.x >> 6;
    int n = __builtin_amdgcn_readfirstlane(blockIdx.x * 4 + wid);
    int f = threadIdx.x & 63;
    unsigned int beg = rowptr[n], end = rowptr[n + 1];
    float4 t4 = *(const float4*)(tbk + (size_t)n * 4);
    float num0 = 0.f, num1 = 0.f, num2 = 0.f, num3 = 0.f;
    float den0 = 0.f, den1 = 0.f, den2 = 0.f, den3 = 0.f;

    for (unsigned int p0 = beg; p0 < end; p0 += 64) {
        unsigned int cnt = end - p0; if (cnt > 64) cnt = 64;
        int s = 0;
        float4 e = {0.f, 0.f, 0.f, 0.f};
        if ((unsigned int)f < cnt) {
            s = srcl[p0 + f];
            float4 sv = *(const float4*)(sbk + (size_t)s * 4);
            float v0 = sv.x + t4.x, v1 = sv.y + t4.y, v2 = sv.z + t4.z, v3 = sv.w + t4.w;
            v0 = (v0 >= 0.f) ? v0 : 0.2f * v0;  v1 = (v1 >= 0.f) ? v1 : 0.2f * v1;
            v2 = (v2 >= 0.f) ? v2 : 0.2f * v2;  v3 = (v3 >= 0.f) ? v3 : 0.2f * v3;
            e.x = __expf(v0); e.y = __expf(v1); e.z = __expf(v2); e.w = __expf(v3);
        }
        lds_src[wid][f] = s;
        lds_ew[wid][f] = e;
        float d0 = e.x, d1 = e.y, d2 = e.z, d3 = e.w;
#pragma unroll
        for (int off = 1; off < 64; off <<= 1) {
            d0 += __shfl_xor(d0, off, 64); d1 += __shfl_xor(d1, off, 64);
            d2 += __shfl_xor(d2, off, 64); d3 += __shfl_xor(d3, off, 64);
        }
        den0 += d0; den1 += d1; den2 += d2; den3 += d3;
        unsigned int jmax = (cnt + 7u) & ~7u;
        for (unsigned int j = 0; j < jmax; j += 8) {
            int ss[8]; float4 ee[8];
#pragma unroll
            for (int u = 0; u < 8; u++) { ss[u] = lds_src[wid][j + u]; ee[u] = lds_ew[wid][j + u]; }
            ushort4 hv[8];
#pragma unroll
            for (int u = 0; u < 8; u++) hv[u] = *(const ushort4*)(hp2k + (size_t)ss[u] * 256 + f * 4);
#pragma unroll
            for (int u = 0; u < 8; u++) {
                num0 += ee[u].x * bf2f(hv[u].x); num1 += ee[u].y * bf2f(hv[u].y);
                num2 += ee[u].z * bf2f(hv[u].z); num3 += ee[u].w * bf2f(hv[u].w);
            }
        }
    }
    float r = 0.25f * (num0 / (den0 + 1e-16f) + num1 / (den1 + 1e-16f)
                     + num2 / (den2 + 1e-16f) + num3 / (den3 + 1e-16f));
    ret[(size_t)n * 256 + k * 64 + f] = f2bf(r);
}

// ---------------------------------------------------------------------------
// qscore_fc: fw1 tile in-register; per-k scores; beta-softmax; fusion frags
// in-register as cols-192..255 A-fragments; fc GEMM + log_softmax fused.
// ---------------------------------------------------------------------------
__global__ __launch_bounds__(256) void qscore_fc(const unsigned short* __restrict__ h,
                                                 const unsigned short* __restrict__ w1T,
                                                 const unsigned short* __restrict__ retA,
                                                 const unsigned short* __restrict__ w2T,
                                                 const unsigned short* __restrict__ mvec,
                                                 const unsigned short* __restrict__ fcwT,
                                                 const unsigned short* __restrict__ bias,
                                                 const int* __restrict__ flagp,
                                                 void* __restrict__ out, int M)
{
    int wave = (blockIdx.x * 256 + threadIdx.x) >> 6;
    int lane = threadIdx.x & 63;
    int m0 = wave * 16;
    if (m0 >= M) return;
    int mi = lane & 15, quad = lane >> 4;

    floatx4 fw[4];
#pragma unroll
    for (int nt = 0; nt < 4; nt++) fw[nt] = (floatx4){0.f, 0.f, 0.f, 0.f};
#pragma unroll
    for (int kk = 0; kk < 4; kk++) {
        short8 a = *(const short8*)(h + (size_t)(m0 + mi) * FIN + kk * 32 + quad * 8);
#pragma unroll
        for (int nt = 0; nt < 4; nt++) {
            short8 b = *(const short8*)(w1T + (size_t)((kk * 4 + quad) * 64 + nt * 16 + mi) * 8);
            fw[nt] = __builtin_amdgcn_mfma_f32_16x16x32_bf16(a, b, fw[nt], 0, 0, 0);
        }
    }

    float pk[3][4];
    short8 afr[3][2];
    for (int k = 0; k < KKIND; k++) {
        floatx4 acc[4];
#pragma unroll
        for (int nt = 0; nt < 4; nt++) acc[nt] = (floatx4){0.f, 0.f, 0.f, 0.f};
#pragma unroll
        for (int kk = 0; kk < 2; kk++) {
            short8 a = *(const short8*)(retA + (size_t)(m0 + mi) * 256 + k * 64 + kk * 32 + quad * 8);
            afr[k][kk] = a;
#pragma unroll
            for (int nt = 0; nt < 4; nt++) {
                short8 b = *(const short8*)(w2T + (size_t)((kk * 4 + quad) * 64 + nt * 16 + mi) * 8);
                acc[nt] = __builtin_amdgcn_mfma_f32_16x16x32_bf16(a, b, acc[nt], 0, 0, 0);
            }
        }
        float part[4] = {0.f, 0.f, 0.f, 0.f};
#pragma unroll
        for (int nt = 0; nt < 4; nt++) {
            int col = nt * 16 + mi;
            float mval = bf2f(mvec[col]);
#pragma unroll
            for (int reg = 0; reg < 4; reg++) {
                float x = acc[nt][reg] + fw[nt][reg];
                float q = 1.f - 2.f / (1.f + __expf(2.f * x));   // tanh, NaN-free
                part[reg] += q * mval;
            }
        }
#pragma unroll
        for (int off = 1; off < 16; off <<= 1)
#pragma unroll
            for (int reg = 0; reg < 4; reg++) part[reg] += __shfl_xor(part[reg], off, 64);
#pragma unroll
        for (int reg = 0; reg < 4; reg++) pk[k][reg] = part[reg];
    }

    int rsel = mi & 3;
    float sv0 = (rsel == 0) ? pk[0][0] : (rsel == 1) ? pk[0][1] : (rsel == 2) ? pk[0][2] : pk[0][3];
    float sv1 = (rsel == 0) ? pk[1][0] : (rsel == 1) ? pk[1][1] : (rsel == 2) ? pk[1][2] : pk[1][3];
    float sv2 = (rsel == 0) ? pk[2][0] : (rsel == 1) ? pk[2][1] : (rsel == 2) ? pk[2][2] : pk[2][3];
    int srcLane = ((mi >> 2) << 4) | mi;
    float s0 = __shfl(sv0, srcLane, 64);
    float s1 = __shfl(sv1, srcLane, 64);
    float s2 = __shfl(sv2, srcLane, 64);
    float mx0 = fmaxf(s0, fmaxf(s1, s2));
    float e0 = __expf(s0 - mx0), e1 = __expf(s1 - mx0), e2 = __expf(s2 - mx0);
    float inv = 1.f / (e0 + e1 + e2);
    float w0 = e0 * inv, w1 = e1 * inv, w2 = e2 * inv;

    short8 ffr[2];
#pragma unroll
    for (int kk = 0; kk < 2; kk++)
#pragma unroll
        for (int j = 0; j < 8; j++) {
            float fu = w0 * bf2f((unsigned short)afr[0][kk][j])
                     + w1 * bf2f((unsigned short)afr[1][kk][j])
                     + w2 * bf2f((unsigned short)afr[2][kk][j]);
            ffr[kk][j] = (short)f2bf(fu);
        }

    floatx4 acc[3];
#pragma unroll
    for (int nt = 0; nt < 3; nt++) acc[nt] = (floatx4){0.f, 0.f, 0.f, 0.f};
#pragma unroll
    for (int kp = 0; kp < 8; kp++) {
        short8 a = (kp < 6) ? afr[kp >> 1][kp & 1] : ffr[kp - 6];
#pragma unroll
        for (int nt = 0; nt < 3; nt++) {
            short8 b = *(const short8*)(fcwT + (size_t)((kp * 4 + quad) * 48 + nt * 16 + mi) * 8);
            acc[nt] = __builtin_amdgcn_mfma_f32_16x16x32_bf16(a, b, acc[nt], 0, 0, 0);
        }
    }
    int fl = *flagp;
    float bv[3]; bool ok[3];
#pragma unroll
    for (int nt = 0; nt < 3; nt++) {
        int col = nt * 16 + mi;
        ok[nt] = (col < NCLS);
        bv[nt] = ok[nt] ? bf2f(bias[col]) : 0.f;
    }
#pragma unroll
    for (int reg = 0; reg < 4; reg++) {
        float v[3];
#pragma unroll
        for (int nt = 0; nt < 3; nt++)
            v[nt] = ok[nt] ? (acc[nt][reg] + bv[nt]) : -3.4e38f;
        float mx = fmaxf(fmaxf(v[0], v[1]), v[2]);
#pragma unroll
        for (int off = 1; off < 16; off <<= 1) mx = fmaxf(mx, __shfl_xor(mx, off, 64));
        float s = 0.f;
#pragma unroll
        for (int nt = 0; nt < 3; nt++) s += ok[nt] ? __expf(v[nt] - mx) : 0.f;
#pragma unroll
        for (int off = 1; off < 16; off <<= 1) s += __shfl_xor(s, off, 64);
        float lse = mx + __logf(s);
        int row = m0 + quad * 4 + reg;
#pragma unroll
        for (int nt = 0; nt < 3; nt++) {
            int col = nt * 16 + mi;
            if (col < NCLS) {
                float ls = v[nt] - lse;
                size_t idx = (size_t)row * NCLS + col;
                if (fl) ((float*)out)[idx] = ls;
                else    ((unsigned short*)out)[idx] = f2bf(ls);
            }
        }
    }
}

extern "C" void kernel_launch(void* const* d_in, const int* in_sizes, int n_in,
                              void* d_out, int out_size, void* d_ws, size_t ws_size,
                              hipStream_t stream)
{
    (void)in_sizes; (void)n_in; (void)out_size;
    const int* ei = (const int*)d_in[1];

    char* ws = (char*)d_ws;
    unsigned short* conv = (unsigned short*)ws;                 // 13,044,944 B
    unsigned short* hc   = conv + OFF_H;
    unsigned short* wc   = conv + OFF_W;
    unsigned short* asrc = conv + OFF_ASRC;
    unsigned short* atrg = conv + OFF_ATRG;
    unsigned short* w1c  = conv + OFF_W1;
    unsigned short* w2c  = conv + OFF_W2;
    unsigned short* mc   = conv + OFF_M;
    unsigned short* fcwc = conv + OFF_FCW;
    unsigned short* fcbc = conv + OFF_FCB;
    int* flag             = (int*)(ws + 13044944);
    unsigned short* wT    = (unsigned short*)(ws + 13045248);   //    196,608 B
    unsigned short* w1T   = (unsigned short*)(ws + 13241856);   //     16,384 B
    unsigned short* w2T   = (unsigned short*)(ws + 13258240);   //      8,192 B
    unsigned short* fcwT  = (unsigned short*)(ws + 13266432);   //     24,576 B
    unsigned short* bst   = (unsigned short*)(ws + 13291008);   //     24,576 B
    unsigned int* partials= (unsigned int*)(ws + 13315584);     //        256 B
    unsigned int* cnt     = (unsigned int*)(ws + 13315840);     //    480,000 B
    unsigned int* rowptr  = (unsigned int*)(ws + 13795840);     //    480,256 B
    int* srcl             = (int*)(ws + 14276096);              //  4,800,000 B
    unsigned int* rank    = (unsigned int*)(ws + 19076096);     //  4,800,000 B
    float* sbuf           = (float*)(ws + 23876096);            //  2,400,000 B (3 kinds)
    float* tbuf           = (float*)(ws + 26276096);            //  2,400,000 B
    unsigned short* ret   = (unsigned short*)(ws + 28676096);   // 20,480,000 B
    unsigned int* blkcnt  = (unsigned int*)(ws + 49156096);     //  7,680,000 B
    unsigned short* hp2   = (unsigned short*)(ws + 56836096);   // 25.6 or 76.8 MB

    const size_t NEED_BIG = 56836096ull + 3ull * NN * 256 * 2;  // 133,636,096
    int big = (ws_size >= NEED_BIG) ? 1 : 0;

    detect_kernel<<<1, 256, 0, stream>>>((const unsigned short*)d_in[0], flag);
    conv_kernel<<<(CONV_TOT / 8 + 255) / 256, 256, 0, stream>>>(
        d_in[0], d_in[2], d_in[3], d_in[4], d_in[5], d_in[6], d_in[7], d_in[8], d_in[9],
        flag, conv);

    repack_w<<<48, 256, 0, stream>>>(wc, wT);
    repack_small<<<12, 256, 0, stream>>>(w1c, w2c, fcwc, w1T, w2T, fcwT);
    repack_ast<<<6, 256, 0, stream>>>(asrc, atrg, bst);

    // CSR build via LDS counting sort (no device-scope atomic-returns)
    histL<<<dim3(CHK, 2 * KKIND), 256, 0, stream>>>(ei, blkcnt, rank);
    scanD<<<(KKIND * 2 * HWRD + 255) / 256, 256, 0, stream>>>(blkcnt, cnt);
    scanA<<<dim3(SCB, 3), 256, 0, stream>>>(cnt, partials);
    scanB<<<1, 256, 0, stream>>>(partials, rowptr);
    scanC<<<dim3(SCB, 3), 256, 0, stream>>>(cnt, partials, rowptr);
    scatter3<<<dim3((EE + 1023) / 1024, 3), 256, 0, stream>>>(ei, rowptr, blkcnt, rank, srcl);

    if (big) {
        long long stride = (long long)NN * 256;
        hp_gemm3<<<dim3(NN / 16, 1), 256, 0, stream>>>(hc, wT, hp2, stride, 0, 3);
        st_gemm<<<dim3((NN / 16 + 3) / 4, 3), 256, 0, stream>>>(hp2, stride, bst, sbuf, tbuf, 0);
        for (int k = 0; k < KKIND; k++)
            passB_multi<<<dim3(NUSER / 4, 1), 256, 0, stream>>>(rowptr, srcl, sbuf, tbuf,
                                                                hp2 + (size_t)k * stride, 0, ret, k);
    } else {
        for (int k = 0; k < KKIND; k++) {
            hp_gemm3<<<dim3(NN / 16, 1), 256, 0, stream>>>(hc, wT, hp2, 0, k, 1);
            st_gemm<<<dim3((NN / 16 + 3) / 4, 1), 256, 0, stream>>>(hp2, 0, bst, sbuf, tbuf, k);
            passB_multi<<<dim3(NUSER / 4, 1), 256, 0, stream>>>(rowptr, srcl, sbuf, tbuf,
                                                                hp2, 0, ret, k);
        }
    }

    qscore_fc<<<625, 256, 0, stream>>>(hc, w1T, ret, w2T, mc, fcwT, fcbc, flag, d_out, NUSER);
}

// Round 13
// 323.113 us; speedup vs baseline: 1.1254x; 1.1254x over previous
//
#include <hip/hip_runtime.h>
#include <hip/hip_bf16.h>

#define NN    50000
#define NUSER 40000
#define EE    400000
#define KKIND 3
#define HHEAD 4
#define FIN   128
#define FOUT  64
#define NCLS  40

#define CHK  96            // edge chunks per kind
#define CHE  4167          // edges per chunk (96*4167 >= EE)
#define HALF 20000         // targets per half
#define HWRD 10000         // packed u16-pair words per half

typedef __attribute__((ext_vector_type(8))) short short8;
typedef __attribute__((ext_vector_type(4))) float floatx4;

__device__ __forceinline__ float bf2f(unsigned short u) {
    unsigned int v = ((unsigned int)u) << 16;
    return __uint_as_float(v);
}
__device__ __forceinline__ unsigned short f2bf(float f) {
    unsigned int u = __float_as_uint(f);
    unsigned int r = (u + 0x7FFFu + ((u >> 16) & 1u)) >> 16;  // RNE
    return (unsigned short)r;
}

// conv-region element offsets (u16 elements) — all multiples of 8
#define OFF_H    0
#define OFF_W    6400000
#define OFF_ASRC 6498304
#define OFF_ATRG 6499072
#define OFF_W1   6499840
#define OFF_W2   6508032
#define OFF_M    6512128
#define OFF_FCW  6512192
#define OFF_FCB  6522432
#define CONV_TOT 6522472

// ---------------------------------------------------------------------------
// dtype detect (f32 vs bf16 float inputs)
// ---------------------------------------------------------------------------
__global__ __launch_bounds__(256) void detect_kernel(const unsigned short* __restrict__ hraw,
                                                     int* __restrict__ flag)
{
    __shared__ int cnt;
    if (threadIdx.x == 0) cnt = 0;
    __syncthreads();
    int local = 0;
#pragma unroll
    for (int j = 0; j < 8; j++) {
        unsigned short u = hraw[threadIdx.x * 8 + j];
        int ex = (u >> 7) & 0xFF;
        if (ex >= 0x90) local++;
    }
    atomicAdd(&cnt, local);
    __syncthreads();
    if (threadIdx.x == 0) *flag = (cnt > 100) ? 1 : 0;
}

// 8 u16 elements per thread; segment boundaries all %8==0
__global__ __launch_bounds__(256) void conv_kernel(const void* __restrict__ p0, const void* __restrict__ p2,
                                                   const void* __restrict__ p3, const void* __restrict__ p4,
                                                   const void* __restrict__ p5, const void* __restrict__ p6,
                                                   const void* __restrict__ p7, const void* __restrict__ p8,
                                                   const void* __restrict__ p9,
                                                   const int* __restrict__ flagp,
                                                   unsigned short* __restrict__ dst)
{
    int tid = (blockIdx.x * 256 + threadIdx.x) * 8;
    if (tid >= CONV_TOT) return;
    const void* src; int li;
    if      (tid < OFF_W)    { src = p0; li = tid - OFF_H; }
    else if (tid < OFF_ASRC) { src = p2; li = tid - OFF_W; }
    else if (tid < OFF_ATRG) { src = p3; li = tid - OFF_ASRC; }
    else if (tid < OFF_W1)   { src = p4; li = tid - OFF_ATRG; }
    else if (tid < OFF_W2)   { src = p5; li = tid - OFF_W1; }
    else if (tid < OFF_M)    { src = p6; li = tid - OFF_W2; }
    else if (tid < OFF_FCW)  { src = p7; li = tid - OFF_M; }
    else if (tid < OFF_FCB)  { src = p8; li = tid - OFF_FCW; }
    else                     { src = p9; li = tid - OFF_FCB; }
    if (*flagp) {
        const float* fp = (const float*)src + li;
        float4 x = *(const float4*)fp;
        float4 y = *(const float4*)(fp + 4);
        uint4 o;
        o.x = (unsigned int)f2bf(x.x) | ((unsigned int)f2bf(x.y) << 16);
        o.y = (unsigned int)f2bf(x.z) | ((unsigned int)f2bf(x.w) << 16);
        o.z = (unsigned int)f2bf(y.x) | ((unsigned int)f2bf(y.y) << 16);
        o.w = (unsigned int)f2bf(y.z) | ((unsigned int)f2bf(y.w) << 16);
        *(uint4*)(dst + tid) = o;
    } else {
        *(uint4*)(dst + tid) = *(const uint4*)((const unsigned short*)src + li);
    }
}

// ---------------------------------------------------------------------------
// B-matrix repacks into MFMA fragment layout
// ---------------------------------------------------------------------------
__global__ __launch_bounds__(256) void repack_w(const unsigned short* __restrict__ w,
                                                unsigned short* __restrict__ wT)
{
    int tid = blockIdx.x * 256 + threadIdx.x;       // 3*4*16*64 = 12288
    if (tid >= 12288) return;
    int f = tid & 63, g = (tid >> 6) & 15, h = (tid >> 10) & 3, k = tid >> 12;
    const unsigned short* src = w + (size_t)(k * 4 + h) * 8192 + f;
    unsigned short* dst = wT + (size_t)tid * 8;
#pragma unroll
    for (int j = 0; j < 8; j++) dst[j] = src[(size_t)(g * 8 + j) * 64];
}

__global__ __launch_bounds__(256) void repack_small(const unsigned short* __restrict__ w1,
                                                    const unsigned short* __restrict__ w2,
                                                    const unsigned short* __restrict__ fcw,
                                                    unsigned short* __restrict__ w1T,
                                                    unsigned short* __restrict__ w2T,
                                                    unsigned short* __restrict__ fcwT)
{
    int tid = blockIdx.x * 256 + threadIdx.x;
    if (tid < 1024) {
        int c = tid & 63, g = tid >> 6;
#pragma unroll
        for (int j = 0; j < 8; j++) w1T[(size_t)(g * 64 + c) * 8 + j] = w1[(size_t)(g * 8 + j) * 64 + c];
    } else if (tid < 1536) {
        int t = tid - 1024; int c = t & 63, g = t >> 6;
#pragma unroll
        for (int j = 0; j < 8; j++) w2T[(size_t)(g * 64 + c) * 8 + j] = w2[(size_t)(g * 8 + j) * 64 + c];
    } else if (tid < 3072) {
        int t = tid - 1536; int c = t % 48, g = t / 48;
#pragma unroll
        for (int j = 0; j < 8; j++)
            fcwT[(size_t)(g * 48 + c) * 8 + j] = (c < NCLS) ? fcw[(size_t)(g * 8 + j) * NCLS + c] : (unsigned short)0;
    }
}

// ---------------------------------------------------------------------------
// repack_ast: sparse 256x16 Bst per kind in fragment layout.
// ---------------------------------------------------------------------------
__global__ __launch_bounds__(256) void repack_ast(const unsigned short* __restrict__ asrc_all,
                                                  const unsigned short* __restrict__ atrg_all,
                                                  unsigned short* __restrict__ bst)
{
    int tid = blockIdx.x * 256 + threadIdx.x;       // 3*32*16 = 1536
    if (tid >= 1536) return;
    int c = tid & 15, g = (tid >> 4) & 31, k = tid >> 9;
    const unsigned short* ask = asrc_all + k * 256;   // [h][f]
    const unsigned short* atk = atrg_all + k * 256;
    unsigned short* dst = bst + (size_t)tid * 8;
#pragma unroll
    for (int j = 0; j < 8; j++) {
        int kd = g * 8 + j;
        int f = kd >> 2, hh = kd & 3;
        unsigned short v = 0;
        if (c < 4)      { if (hh == c)     v = ask[c * 64 + f]; }
        else if (c < 8) { if (hh == c - 4) v = atk[(c - 4) * 64 + f]; }
        dst[j] = v;
    }
}

// ---------------------------------------------------------------------------
// histL: LDS counting-sort rank pass.  Grid (CHK, 2*KKIND).  40 KB LDS of
// packed u16 counters; CONTIGUOUS 40 KB coalesced dump (no strided write
// amplification); 576 blocks for occupancy.
// ---------------------------------------------------------------------------
__global__ __launch_bounds__(256) void histL(const int* __restrict__ ei,
                                             unsigned int* __restrict__ blkcnt,
                                             unsigned int* __restrict__ rank)
{
    __shared__ unsigned int lcnt[HWRD];   // 40 KB
    int b = blockIdx.x;
    int hf = blockIdx.y & 1, k = blockIdx.y >> 1;
    const int* trg = ei + (size_t)k * 2 * EE + EE;
    unsigned int* rk = rank + (size_t)k * EE;
    for (int i = threadIdx.x; i < HWRD; i += 256) lcnt[i] = 0u;
    __syncthreads();
    int beg = b * CHE;
    int end = beg + CHE; if (end > EE) end = EE;
    int tbase = hf * HALF;
    for (int e = beg + threadIdx.x; e < end; e += 256) {
        int tn = trg[e];
        unsigned int lt = (unsigned int)(tn - tbase);
        if (lt < HALF) {
            unsigned int sh = (lt & 1u) * 16u;
            unsigned int old = atomicAdd(&lcnt[lt >> 1], 1u << sh);
            rk[e] = (old >> sh) & 0xFFFFu;
        }
    }
    __syncthreads();
    unsigned int* dst = blkcnt + ((size_t)blockIdx.y * CHK + b) * HWRD;
    for (int w = threadIdx.x; w < HWRD; w += 256)
        dst[w] = lcnt[w];
}

// ---------------------------------------------------------------------------
// scanD: per (kind,half,word) exclusive prefix over CHK chunk counts (packed
// u16 pairs), in place.  Thread owns word w; per-iteration across-thread
// access is contiguous (coalesced).  Emits per-target totals into cnt.
// ---------------------------------------------------------------------------
__global__ __launch_bounds__(256) void scanD(unsigned int* __restrict__ blkcnt,
                                             unsigned int* __restrict__ cnt)
{
    int tid = blockIdx.x * 256 + threadIdx.x;      // KKIND*2*HWRD = 60000
    if (tid >= KKIND * 2 * HWRD) return;
    int w = tid % HWRD;
    int kh = tid / HWRD;
    int hf = kh & 1, k = kh >> 1;
    unsigned int* base = blkcnt + (size_t)kh * CHK * HWRD + w;
    unsigned int run = 0;
    for (int b = 0; b < CHK; b++) {
        unsigned int v = base[(size_t)b * HWRD];
        base[(size_t)b * HWRD] = run;
        run += v;
    }
    int t = hf * HALF + w * 2;
    cnt[(size_t)k * NUSER + t]     = run & 0xFFFFu;
    cnt[(size_t)k * NUSER + t + 1] = run >> 16;
}

#define SCB 20
__global__ __launch_bounds__(256) void scanA(const unsigned int* __restrict__ cnt,
                                             unsigned int* __restrict__ partials)
{
    int k = blockIdx.y, b = blockIdx.x;
    const unsigned int* c = cnt + (size_t)k * NUSER;
    int base = b * 2048 + threadIdx.x * 8;
    unsigned int s = 0;
#pragma unroll
    for (int j = 0; j < 8; j++) { int idx = base + j; if (idx < NUSER) s += c[idx]; }
#pragma unroll
    for (int off = 1; off < 64; off <<= 1) s += __shfl_xor(s, off, 64);
    __shared__ unsigned int wsum[4];
    int lane = threadIdx.x & 63, wid = threadIdx.x >> 6;
    if (lane == 0) wsum[wid] = s;
    __syncthreads();
    if (threadIdx.x == 0) partials[k * SCB + b] = wsum[0] + wsum[1] + wsum[2] + wsum[3];
}

__global__ __launch_bounds__(256) void scanB(unsigned int* __restrict__ partials,
                                             unsigned int* __restrict__ rowptr)
{
    int wid = threadIdx.x >> 6, lane = threadIdx.x & 63;
    if (wid >= KKIND) return;
    unsigned int v = (lane < SCB) ? partials[wid * SCB + lane] : 0u;
    unsigned int inc = v;
#pragma unroll
    for (int off = 1; off < 32; off <<= 1) {
        unsigned int u = __shfl_up(inc, off, 64);
        if (lane >= off) inc += u;
    }
    if (lane < SCB) partials[wid * SCB + lane] = inc - v;
    if (lane == SCB - 1) rowptr[(size_t)wid * (NUSER + 1) + NUSER] = inc;
}

__global__ __launch_bounds__(256) void scanC(const unsigned int* __restrict__ cnt,
                                             const unsigned int* __restrict__ partials,
                                             unsigned int* __restrict__ rowptr)
{
    int k = blockIdx.y, b = blockIdx.x;
    const unsigned int* c = cnt + (size_t)k * NUSER;
    unsigned int* rp = rowptr + (size_t)k * (NUSER + 1);
    int lane = threadIdx.x & 63, wid = threadIdx.x >> 6;
    int base = b * 2048 + threadIdx.x * 8;
    unsigned int vals[8]; unsigned int s = 0;
#pragma unroll
    for (int j = 0; j < 8; j++) { int idx = base + j; vals[j] = (idx < NUSER) ? c[idx] : 0u; s += vals[j]; }
    unsigned int inc = s;
#pragma unroll
    for (int off = 1; off < 64; off <<= 1) {
        unsigned int u = __shfl_up(inc, off, 64);
        if (lane >= off) inc += u;
    }
    __shared__ unsigned int wsum[4];
    if (lane == 63) wsum[wid] = inc;
    __syncthreads();
    unsigned int woff = 0;
    for (int i = 0; i < wid; i++) woff += wsum[i];
    unsigned int run = partials[k * SCB + b] + woff + (inc - s);
#pragma unroll
    for (int j = 0; j < 8; j++) {
        int idx = base + j;
        if (idx < NUSER) { rp[idx] = run; run += vals[j]; }
    }
}

// atomic-free scatter: p = rowptr[tn] + blkpos[kh][chunk][tn] + rank[e]
__global__ __launch_bounds__(256) void scatter3(const int* __restrict__ ei,
                                                const unsigned int* __restrict__ rowptr,
                                                const unsigned int* __restrict__ blkpos,
                                                const unsigned int* __restrict__ rank,
                                                int* __restrict__ srcl)
{
    int k = blockIdx.y;
    const int* srcA = ei + (size_t)k * 2 * EE;
    const int* trg = srcA + EE;
    const unsigned int* rp = rowptr + (size_t)k * (NUSER + 1);
    const unsigned int* rk = rank + (size_t)k * EE;
    int* sl = srcl + (size_t)k * EE;
    int e0 = blockIdx.x * 1024 + threadIdx.x;
#pragma unroll
    for (int j = 0; j < 4; j++) {
        int e = e0 + j * 256;
        if (e >= EE) continue;
        int tn = trg[e];
        if (tn >= NUSER) continue;
        int hf = (tn >= HALF) ? 1 : 0;
        int lt = tn - hf * HALF;
        int b = e / CHE;
        unsigned int pos = blkpos[((size_t)(k * 2 + hf) * CHK + b) * HWRD + (lt >> 1)];
        pos = (pos >> ((lt & 1) * 16)) & 0xFFFFu;
        sl[rp[tn] + pos + rk[e]] = srcA[e];
    }
}

// ---------------------------------------------------------------------------
// hp_gemm3: one wave per (16 rows x 16-col quadrant), looping kcnt kinds —
// A-fragments loaded once.  hp2 layout [n][f][4heads].
// ---------------------------------------------------------------------------
__global__ __launch_bounds__(256) void hp_gemm3(const unsigned short* __restrict__ h,
                                                const unsigned short* __restrict__ wTall,
                                                unsigned short* __restrict__ hp2,
                                                long long hp2_stride, int kbeg, int kcnt)
{
    int q = threadIdx.x >> 6;            // col quadrant 0..3
    int lane = threadIdx.x & 63;
    int m0 = blockIdx.x * 16;
    int mi = lane & 15, quad = lane >> 4;

    short8 a[4];
    const unsigned short* hrow = h + (size_t)(m0 + mi) * FIN + quad * 8;
#pragma unroll
    for (int kk = 0; kk < 4; kk++) a[kk] = *(const short8*)(hrow + kk * 32);

    int fc = q * 16 + mi;
    for (int kq = 0; kq < kcnt; kq++) {
        const unsigned short* wTk = wTall + (size_t)(kbeg + kq) * 32768;
        unsigned short* hp2k = hp2 + (size_t)kq * hp2_stride;
        floatx4 acc4[4];
#pragma unroll
        for (int hh = 0; hh < 4; hh++) {
            floatx4 acc = {0.f, 0.f, 0.f, 0.f};
#pragma unroll
            for (int kk = 0; kk < 4; kk++) {
                short8 b = *(const short8*)(wTk + (size_t)((hh * 16 + kk * 4 + quad) * 64 + fc) * 8);
                acc = __builtin_amdgcn_mfma_f32_16x16x32_bf16(a[kk], b, acc, 0, 0, 0);
            }
            acc4[hh] = acc;
        }
#pragma unroll
        for (int reg = 0; reg < 4; reg++) {
            ushort4 pk;
            pk.x = f2bf(acc4[0][reg]); pk.y = f2bf(acc4[1][reg]);
            pk.z = f2bf(acc4[2][reg]); pk.w = f2bf(acc4[3][reg]);
            int row = m0 + quad * 4 + reg;
            *(ushort4*)(hp2k + (size_t)row * 256 + fc * 4) = pk;
        }
    }
}

// ---------------------------------------------------------------------------
// st_gemm: [s|t](16 nodes, 8 cols) = hp2-rows @ Bst via 8 MFMAs per wave.
// ---------------------------------------------------------------------------
__global__ __launch_bounds__(256) void st_gemm(const unsigned short* __restrict__ hp2,
                                               long long hp2_stride,
                                               const unsigned short* __restrict__ bst,
                                               float* __restrict__ sb, float* __restrict__ tb,
                                               int kbeg)
{
    int kq = blockIdx.y, k = kbeg + kq;
    const unsigned short* hp2k = hp2 + (size_t)kq * hp2_stride;
    const unsigned short* bk = bst + (size_t)k * 4096;
    float* sbk = sb + (size_t)k * NN * 4;
    float* tbk = tb + (size_t)k * NN * 4;

    int wave = threadIdx.x >> 6;
    int lane = threadIdx.x & 63;
    int m0 = (blockIdx.x * 4 + wave) * 16;
    if (m0 >= NN) return;
    int mi = lane & 15, quad = lane >> 4;

    floatx4 acc = {0.f, 0.f, 0.f, 0.f};
#pragma unroll
    for (int kk = 0; kk < 8; kk++) {
        short8 a = *(const short8*)(hp2k + (size_t)(m0 + mi) * 256 + kk * 32 + quad * 8);
        short8 b = *(const short8*)(bk + (size_t)((kk * 4 + quad) * 16 + mi) * 8);
        acc = __builtin_amdgcn_mfma_f32_16x16x32_bf16(a, b, acc, 0, 0, 0);
    }
    if (mi < 8) {
#pragma unroll
        for (int reg = 0; reg < 4; reg++) {
            int n = m0 + quad * 4 + reg;
            if (mi < 4) sbk[n * 4 + mi] = acc[reg];
            else        tbk[n * 4 + (mi - 4)] = acc[reg];
        }
    }
}

// ---------------------------------------------------------------------------
// passB_multi: wave per (user node, kind); two-phase LDS-broadcast edge loop.
// ---------------------------------------------------------------------------
__global__ __launch_bounds__(256) void passB_multi(const unsigned int* __restrict__ rowptr_all,
                                                   const int* __restrict__ srcl_all,
                                                   const float* __restrict__ sb,
                                                   const float* __restrict__ tb,
                                                   const unsigned short* __restrict__ hp2,
                                                   long long hp2_stride,
                                                   unsigned short* __restrict__ ret, int kbeg)
{
    __shared__ int    lds_src[4][64];
    __shared__ float4 lds_ew[4][64];
    int kq = blockIdx.y, k = kbeg + kq;
    const unsigned int* rowptr = rowptr_all + (size_t)k * (NUSER + 1);
    const int* srcl = srcl_all + (size_t)k * EE;
    const float* sbk = sb + (size_t)k * NN * 4;
    const float* tbk = tb + (size_t)k * NN * 4;
    const unsigned short* hp2k = hp2 + (size_t)kq * hp2_stride;

    int wid = threadIdx.x >> 6;
    int n = __builtin_amdgcn_readfirstlane(blockIdx.x * 4 + wid);
    int f = threadIdx.x & 63;
    unsigned int beg = rowptr[n], end = rowptr[n + 1];
    float4 t4 = *(const float4*)(tbk + (size_t)n * 4);
    float num0 = 0.f, num1 = 0.f, num2 = 0.f, num3 = 0.f;
    float den0 = 0.f, den1 = 0.f, den2 = 0.f, den3 = 0.f;

    for (unsigned int p0 = beg; p0 < end; p0 += 64) {
        unsigned int cnt = end - p0; if (cnt > 64) cnt = 64;
        int s = 0;
        float4 e = {0.f, 0.f, 0.f, 0.f};
        if ((unsigned int)f < cnt) {
            s = srcl[p0 + f];
            float4 sv = *(const float4*)(sbk + (size_t)s * 4);
            float v0 = sv.x + t4.x, v1 = sv.y + t4.y, v2 = sv.z + t4.z, v3 = sv.w + t4.w;
            v0 = (v0 >= 0.f) ? v0 : 0.2f * v0;  v1 = (v1 >= 0.f) ? v1 : 0.2f * v1;
            v2 = (v2 >= 0.f) ? v2 : 0.2f * v2;  v3 = (v3 >= 0.f) ? v3 : 0.2f * v3;
            e.x = __expf(v0); e.y = __expf(v1); e.z = __expf(v2); e.w = __expf(v3);
        }
        lds_src[wid][f] = s;
        lds_ew[wid][f] = e;
        float d0 = e.x, d1 = e.y, d2 = e.z, d3 = e.w;
#pragma unroll
        for (int off = 1; off < 64; off <<= 1) {
            d0 += __shfl_xor(d0, off, 64); d1 += __shfl_xor(d1, off, 64);
            d2 += __shfl_xor(d2, off, 64); d3 += __shfl_xor(d3, off, 64);
        }
        den0 += d0; den1 += d1; den2 += d2; den3 += d3;
        unsigned int jmax = (cnt + 7u) & ~7u;
        for (unsigned int j = 0; j < jmax; j += 8) {
            int ss[8]; float4 ee[8];
#pragma unroll
            for (int u = 0; u < 8; u++) { ss[u] = lds_src[wid][j + u]; ee[u] = lds_ew[wid][j + u]; }
            ushort4 hv[8];
#pragma unroll
            for (int u = 0; u < 8; u++) hv[u] = *(const ushort4*)(hp2k + (size_t)ss[u] * 256 + f * 4);
#pragma unroll
            for (int u = 0; u < 8; u++) {
                num0 += ee[u].x * bf2f(hv[u].x); num1 += ee[u].y * bf2f(hv[u].y);
                num2 += ee[u].z * bf2f(hv[u].z); num3 += ee[u].w * bf2f(hv[u].w);
            }
        }
    }
    float r = 0.25f * (num0 / (den0 + 1e-16f) + num1 / (den1 + 1e-16f)
                     + num2 / (den2 + 1e-16f) + num3 / (den3 + 1e-16f));
    ret[(size_t)n * 256 + k * 64 + f] = f2bf(r);
}

// ---------------------------------------------------------------------------
// qscore_fc: fw1 tile in-register; per-k scores; beta-softmax; fusion frags
// in-register as cols-192..255 A-fragments; fc GEMM + log_softmax fused.
// ---------------------------------------------------------------------------
__global__ __launch_bounds__(256) void qscore_fc(const unsigned short* __restrict__ h,
                                                 const unsigned short* __restrict__ w1T,
                                                 const unsigned short* __restrict__ retA,
                                                 const unsigned short* __restrict__ w2T,
                                                 const unsigned short* __restrict__ mvec,
                                                 const unsigned short* __restrict__ fcwT,
                                                 const unsigned short* __restrict__ bias,
                                                 const int* __restrict__ flagp,
                                                 void* __restrict__ out, int M)
{
    int wave = (blockIdx.x * 256 + threadIdx.x) >> 6;
    int lane = threadIdx.x & 63;
    int m0 = wave * 16;
    if (m0 >= M) return;
    int mi = lane & 15, quad = lane >> 4;

    floatx4 fw[4];
#pragma unroll
    for (int nt = 0; nt < 4; nt++) fw[nt] = (floatx4){0.f, 0.f, 0.f, 0.f};
#pragma unroll
    for (int kk = 0; kk < 4; kk++) {
        short8 a = *(const short8*)(h + (size_t)(m0 + mi) * FIN + kk * 32 + quad * 8);
#pragma unroll
        for (int nt = 0; nt < 4; nt++) {
            short8 b = *(const short8*)(w1T + (size_t)((kk * 4 + quad) * 64 + nt * 16 + mi) * 8);
            fw[nt] = __builtin_amdgcn_mfma_f32_16x16x32_bf16(a, b, fw[nt], 0, 0, 0);
        }
    }

    float pk[3][4];
    short8 afr[3][2];
    for (int k = 0; k < KKIND; k++) {
        floatx4 acc[4];
#pragma unroll
        for (int nt = 0; nt < 4; nt++) acc[nt] = (floatx4){0.f, 0.f, 0.f, 0.f};
#pragma unroll
        for (int kk = 0; kk < 2; kk++) {
            short8 a = *(const short8*)(retA + (size_t)(m0 + mi) * 256 + k * 64 + kk * 32 + quad * 8);
            afr[k][kk] = a;
#pragma unroll
            for (int nt = 0; nt < 4; nt++) {
                short8 b = *(const short8*)(w2T + (size_t)((kk * 4 + quad) * 64 + nt * 16 + mi) * 8);
                acc[nt] = __builtin_amdgcn_mfma_f32_16x16x32_bf16(a, b, acc[nt], 0, 0, 0);
            }
        }
        float part[4] = {0.f, 0.f, 0.f, 0.f};
#pragma unroll
        for (int nt = 0; nt < 4; nt++) {
            int col = nt * 16 + mi;
            float mval = bf2f(mvec[col]);
#pragma unroll
            for (int reg = 0; reg < 4; reg++) {
                float x = acc[nt][reg] + fw[nt][reg];
                float q = 1.f - 2.f / (1.f + __expf(2.f * x));   // tanh, NaN-free
                part[reg] += q * mval;
            }
        }
#pragma unroll
        for (int off = 1; off < 16; off <<= 1)
#pragma unroll
            for (int reg = 0; reg < 4; reg++) part[reg] += __shfl_xor(part[reg], off, 64);
#pragma unroll
        for (int reg = 0; reg < 4; reg++) pk[k][reg] = part[reg];
    }

    int rsel = mi & 3;
    float sv0 = (rsel == 0) ? pk[0][0] : (rsel == 1) ? pk[0][1] : (rsel == 2) ? pk[0][2] : pk[0][3];
    float sv1 = (rsel == 0) ? pk[1][0] : (rsel == 1) ? pk[1][1] : (rsel == 2) ? pk[1][2] : pk[1][3];
    float sv2 = (rsel == 0) ? pk[2][0] : (rsel == 1) ? pk[2][1] : (rsel == 2) ? pk[2][2] : pk[2][3];
    int srcLane = ((mi >> 2) << 4) | mi;
    float s0 = __shfl(sv0, srcLane, 64);
    float s1 = __shfl(sv1, srcLane, 64);
    float s2 = __shfl(sv2, srcLane, 64);
    float mx0 = fmaxf(s0, fmaxf(s1, s2));
    float e0 = __expf(s0 - mx0), e1 = __expf(s1 - mx0), e2 = __expf(s2 - mx0);
    float inv = 1.f / (e0 + e1 + e2);
    float w0 = e0 * inv, w1 = e1 * inv, w2 = e2 * inv;

    short8 ffr[2];
#pragma unroll
    for (int kk = 0; kk < 2; kk++)
#pragma unroll
        for (int j = 0; j < 8; j++) {
            float fu = w0 * bf2f((unsigned short)afr[0][kk][j])
                     + w1 * bf2f((unsigned short)afr[1][kk][j])
                     + w2 * bf2f((unsigned short)afr[2][kk][j]);
            ffr[kk][j] = (short)f2bf(fu);
        }

    floatx4 acc[3];
#pragma unroll
    for (int nt = 0; nt < 3; nt++) acc[nt] = (floatx4){0.f, 0.f, 0.f, 0.f};
#pragma unroll
    for (int kp = 0; kp < 8; kp++) {
        short8 a = (kp < 6) ? afr[kp >> 1][kp & 1] : ffr[kp - 6];
#pragma unroll
        for (int nt = 0; nt < 3; nt++) {
            short8 b = *(const short8*)(fcwT + (size_t)((kp * 4 + quad) * 48 + nt * 16 + mi) * 8);
            acc[nt] = __builtin_amdgcn_mfma_f32_16x16x32_bf16(a, b, acc[nt], 0, 0, 0);
        }
    }
    int fl = *flagp;
    float bv[3]; bool ok[3];
#pragma unroll
    for (int nt = 0; nt < 3; nt++) {
        int col = nt * 16 + mi;
        ok[nt] = (col < NCLS);
        bv[nt] = ok[nt] ? bf2f(bias[col]) : 0.f;
    }
#pragma unroll
    for (int reg = 0; reg < 4; reg++) {
        float v[3];
#pragma unroll
        for (int nt = 0; nt < 3; nt++)
            v[nt] = ok[nt] ? (acc[nt][reg] + bv[nt]) : -3.4e38f;
        float mx = fmaxf(fmaxf(v[0], v[1]), v[2]);
#pragma unroll
        for (int off = 1; off < 16; off <<= 1) mx = fmaxf(mx, __shfl_xor(mx, off, 64));
        float s = 0.f;
#pragma unroll
        for (int nt = 0; nt < 3; nt++) s += ok[nt] ? __expf(v[nt] - mx) : 0.f;
#pragma unroll
        for (int off = 1; off < 16; off <<= 1) s += __shfl_xor(s, off, 64);
        float lse = mx + __logf(s);
        int row = m0 + quad * 4 + reg;
#pragma unroll
        for (int nt = 0; nt < 3; nt++) {
            int col = nt * 16 + mi;
            if (col < NCLS) {
                float ls = v[nt] - lse;
                size_t idx = (size_t)row * NCLS + col;
                if (fl) ((float*)out)[idx] = ls;
                else    ((unsigned short*)out)[idx] = f2bf(ls);
            }
        }
    }
}

extern "C" void kernel_launch(void* const* d_in, const int* in_sizes, int n_in,
                              void* d_out, int out_size, void* d_ws, size_t ws_size,
                              hipStream_t stream)
{
    (void)in_sizes; (void)n_in; (void)out_size;
    const int* ei = (const int*)d_in[1];

    char* ws = (char*)d_ws;
    unsigned short* conv = (unsigned short*)ws;                 // 13,044,944 B
    unsigned short* hc   = conv + OFF_H;
    unsigned short* wc   = conv + OFF_W;
    unsigned short* asrc = conv + OFF_ASRC;
    unsigned short* atrg = conv + OFF_ATRG;
    unsigned short* w1c  = conv + OFF_W1;
    unsigned short* w2c  = conv + OFF_W2;
    unsigned short* mc   = conv + OFF_M;
    unsigned short* fcwc = conv + OFF_FCW;
    unsigned short* fcbc = conv + OFF_FCB;
    int* flag             = (int*)(ws + 13044944);
    unsigned short* wT    = (unsigned short*)(ws + 13045248);   //    196,608 B
    unsigned short* w1T   = (unsigned short*)(ws + 13241856);   //     16,384 B
    unsigned short* w2T   = (unsigned short*)(ws + 13258240);   //      8,192 B
    unsigned short* fcwT  = (unsigned short*)(ws + 13266432);   //     24,576 B
    unsigned short* bst   = (unsigned short*)(ws + 13291008);   //     24,576 B
    unsigned int* partials= (unsigned int*)(ws + 13315584);     //        256 B
    unsigned int* cnt     = (unsigned int*)(ws + 13315840);     //    480,000 B
    unsigned int* rowptr  = (unsigned int*)(ws + 13795840);     //    480,256 B
    int* srcl             = (int*)(ws + 14276096);              //  4,800,000 B
    unsigned int* rank    = (unsigned int*)(ws + 19076096);     //  4,800,000 B
    float* sbuf           = (float*)(ws + 23876096);            //  2,400,000 B (3 kinds)
    float* tbuf           = (float*)(ws + 26276096);            //  2,400,000 B
    unsigned short* ret   = (unsigned short*)(ws + 28676096);   // 20,480,000 B
    unsigned int* blkcnt  = (unsigned int*)(ws + 49156096);     // 23,040,000 B
    unsigned short* hp2   = (unsigned short*)(ws + 72196096);   // 25.6 or 76.8 MB

    const size_t NEED_BIG = 72196096ull + 3ull * NN * 256 * 2;  // 148,996,096
    int big = (ws_size >= NEED_BIG) ? 1 : 0;

    detect_kernel<<<1, 256, 0, stream>>>((const unsigned short*)d_in[0], flag);
    conv_kernel<<<(CONV_TOT / 8 + 255) / 256, 256, 0, stream>>>(
        d_in[0], d_in[2], d_in[3], d_in[4], d_in[5], d_in[6], d_in[7], d_in[8], d_in[9],
        flag, conv);

    repack_w<<<48, 256, 0, stream>>>(wc, wT);
    repack_small<<<12, 256, 0, stream>>>(w1c, w2c, fcwc, w1T, w2T, fcwT);
    repack_ast<<<6, 256, 0, stream>>>(asrc, atrg, bst);

    // CSR build via LDS counting sort (coalesced dump, 576 blocks)
    histL<<<dim3(CHK, 2 * KKIND), 256, 0, stream>>>(ei, blkcnt, rank);
    scanD<<<(KKIND * 2 * HWRD + 255) / 256, 256, 0, stream>>>(blkcnt, cnt);
    scanA<<<dim3(SCB, 3), 256, 0, stream>>>(cnt, partials);
    scanB<<<1, 256, 0, stream>>>(partials, rowptr);
    scanC<<<dim3(SCB, 3), 256, 0, stream>>>(cnt, partials, rowptr);
    scatter3<<<dim3((EE + 1023) / 1024, 3), 256, 0, stream>>>(ei, rowptr, blkcnt, rank, srcl);

    if (big) {
        long long stride = (long long)NN * 256;
        hp_gemm3<<<dim3(NN / 16, 1), 256, 0, stream>>>(hc, wT, hp2, stride, 0, 3);
        st_gemm<<<dim3((NN / 16 + 3) / 4, 3), 256, 0, stream>>>(hp2, stride, bst, sbuf, tbuf, 0);
        for (int k = 0; k < KKIND; k++)
            passB_multi<<<dim3(NUSER / 4, 1), 256, 0, stream>>>(rowptr, srcl, sbuf, tbuf,
                                                                hp2 + (size_t)k * stride, 0, ret, k);
    } else {
        for (int k = 0; k < KKIND; k++) {
            hp_gemm3<<<dim3(NN / 16, 1), 256, 0, stream>>>(hc, wT, hp2, 0, k, 1);
            st_gemm<<<dim3((NN / 16 + 3) / 4, 1), 256, 0, stream>>>(hp2, 0, bst, sbuf, tbuf, k);
            passB_multi<<<dim3(NUSER / 4, 1), 256, 0, stream>>>(rowptr, srcl, sbuf, tbuf,
                                                                hp2, 0, ret, k);
        }
    }

    qscore_fc<<<625, 256, 0, stream>>>(hc, w1T, ret, w2T, mc, fcwT, fcbc, flag, d_out, NUSER);
}